// Round 1
// baseline (982.001 us; speedup 1.0000x reference)
//
#include <hip/hip_runtime.h>
#include <hip/hip_bf16.h>

// GCN: 2-layer GraphConv + dense head. fp32 baseline, CSR-based aggregation.
// N0=100000, N1=20000, N2=4000, E1=500000, E2=100000, F=H=512, C=10.

static constexpr int N0 = 100000;
static constexpr int N1 = 20000;
static constexpr int N2 = 4000;
static constexpr int H  = 512;
static constexpr int C  = 10;

// ---------------- CSR build ----------------

__global__ void count_k(const int* __restrict__ dst, int* __restrict__ cnt, int E) {
    int g = blockIdx.x * 256 + threadIdx.x;
    if (g < E) atomicAdd(&cnt[dst[g]], 1);
}

// single-block exclusive scan over n counters -> rs[0..n]
__global__ __launch_bounds__(1024)
void exscan_k(const int* __restrict__ cnt, int* __restrict__ rs, int n) {
    __shared__ int part[1024];
    int t = threadIdx.x;
    int chunk = (n + 1023) >> 10;
    int b = t * chunk;
    int e = min(b + chunk, n);
    int s = 0;
    for (int i = b; i < e; ++i) s += cnt[i];
    part[t] = s;
    __syncthreads();
    for (int off = 1; off < 1024; off <<= 1) {
        int add = (t >= off) ? part[t - off] : 0;
        __syncthreads();
        part[t] += add;
        __syncthreads();
    }
    int base = (t == 0) ? 0 : part[t - 1];
    for (int i = b; i < e; ++i) { rs[i] = base; base += cnt[i]; }
    if (t == 1023) rs[n] = part[1023];
}

__global__ void fill_k(const int* __restrict__ src, const int* __restrict__ dst,
                       const int* __restrict__ rs, int* __restrict__ cursor,
                       int* __restrict__ eidx, int E) {
    int g = blockIdx.x * 256 + threadIdx.x;
    if (g < E) {
        int d = dst[g];
        int pos = atomicAdd(&cursor[d], 1);
        eidx[rs[d] + pos] = src[g];
    }
}

// ---------------- aggregation: one block per target node ----------------
// out[node, :] = sum over edges of x[src, :]   (written, not accumulated)
__global__ __launch_bounds__(128)
void aggregate_k(const float* __restrict__ x, const int* __restrict__ rs,
                 const int* __restrict__ eidx, float* __restrict__ out) {
    int node = blockIdx.x;
    int t = threadIdx.x;  // 0..127, features t*4 .. t*4+3
    int s = rs[node], e = rs[node + 1];
    float4 acc = make_float4(0.f, 0.f, 0.f, 0.f);
    for (int i = s; i < e; ++i) {
        const float4* row = (const float4*)(x + (size_t)eidx[i] * H);
        float4 v = row[t];
        acc.x += v.x; acc.y += v.y; acc.z += v.z; acc.w += v.w;
    }
    ((float4*)(out + (size_t)node * H))[t] = acc;
}

// ---------------- tiled fp32 GEMM, dual-A accumulate, bias, optional relu ---
// C[M,N] = A1[M,K]@B1[K,N] (+ A2[M,K]@B2[K,N]) + bias[N]; relu optional.
// BM=BN=64, BK=16, 256 threads, 4x4 per thread.
__global__ __launch_bounds__(256)
void gemm_dual_k(const float* __restrict__ A1, const float* __restrict__ B1,
                 const float* __restrict__ A2, const float* __restrict__ B2,
                 const float* __restrict__ bias, float* __restrict__ Cmat,
                 int M, int N, int K, int relu) {
    __shared__ __align__(16) float As[16][68];
    __shared__ __align__(16) float Bs[16][68];
    int bm = blockIdx.y * 64;
    int bn = blockIdx.x * 64;
    int tid = threadIdx.x;
    int tx = tid & 15, ty = tid >> 4;
    float acc[4][4] = {};

    for (int pass = 0; pass < 2; ++pass) {
        const float* A = pass ? A2 : A1;
        const float* B = pass ? B2 : B1;
        if (!A) continue;
        for (int k0 = 0; k0 < K; k0 += 16) {
            {   // A tile: 64 rows x 16 k, one float4/thread, transposed into LDS
                int row = tid >> 2;
                int kk  = (tid & 3) * 4;
                int gr = bm + row;
                float4 v = make_float4(0.f, 0.f, 0.f, 0.f);
                if (gr < M) v = *(const float4*)(A + (size_t)gr * K + k0 + kk);
                As[kk + 0][row] = v.x;
                As[kk + 1][row] = v.y;
                As[kk + 2][row] = v.z;
                As[kk + 3][row] = v.w;
            }
            {   // B tile: 16 k x 64 n, one float4/thread
                int krow = tid >> 4;
                int nn = (tid & 15) * 4;
                float4 v = *(const float4*)(B + (size_t)(k0 + krow) * N + bn + nn);
                *(float4*)&Bs[krow][nn] = v;
            }
            __syncthreads();
#pragma unroll
            for (int k = 0; k < 16; ++k) {
                float4 a = *(const float4*)&As[k][ty * 4];
                float4 b = *(const float4*)&Bs[k][tx * 4];
                float av[4] = {a.x, a.y, a.z, a.w};
                float bv[4] = {b.x, b.y, b.z, b.w};
#pragma unroll
                for (int i = 0; i < 4; ++i)
#pragma unroll
                    for (int j = 0; j < 4; ++j)
                        acc[i][j] += av[i] * bv[j];
            }
            __syncthreads();
        }
    }
#pragma unroll
    for (int i = 0; i < 4; ++i) {
        int gm = bm + ty * 4 + i;
        if (gm >= M) continue;
#pragma unroll
        for (int j = 0; j < 4; ++j) {
            int gn = bn + tx * 4 + j;
            float v = acc[i][j] + bias[gn];
            if (relu) v = fmaxf(v, 0.f);
            Cmat[(size_t)gm * N + gn] = v;
        }
    }
}

// ---------------- head: out[m,c] = T[m,:] . Whead[:,c] + bhead[c] ----------
__global__ void head_k(const float* __restrict__ T, const float* __restrict__ Wh,
                       const float* __restrict__ bh, float* __restrict__ out, int M) {
    int g = blockIdx.x * 256 + threadIdx.x;
    if (g >= M * C) return;
    int m = g / C, c = g % C;
    float acc = bh[c];
    const float* row = T + (size_t)m * H;
#pragma unroll 4
    for (int k = 0; k < H; ++k) acc += row[k] * Wh[k * C + c];
    out[g] = acc;
}

extern "C" void kernel_launch(void* const* d_in, const int* in_sizes, int n_in,
                              void* d_out, int out_size, void* d_ws, size_t ws_size,
                              hipStream_t stream) {
    const float* x      = (const float*)d_in[0];
    const int*   src1   = (const int*)d_in[1];
    const int*   dst1   = (const int*)d_in[2];
    const int*   src2   = (const int*)d_in[3];
    const int*   dst2   = (const int*)d_in[4];
    const float* Wrel1  = (const float*)d_in[5];
    const float* brel1  = (const float*)d_in[6];
    const float* Wroot1 = (const float*)d_in[7];
    const float* Wrel2  = (const float*)d_in[8];
    const float* brel2  = (const float*)d_in[9];
    const float* Wroot2 = (const float*)d_in[10];
    const float* Wlin   = (const float*)d_in[11];
    const float* blin   = (const float*)d_in[12];
    const float* Whead  = (const float*)d_in[13];
    const float* bhead  = (const float*)d_in[14];
    float* out = (float*)d_out;

    const int E1 = in_sizes[1];
    const int E2 = in_sizes[3];

    // ---- workspace layout ----
    float* f = (float*)d_ws;
    float* agg1 = f;                         // N1*H = 10,240,000 floats
    float* h    = f + (size_t)N1 * H;        // 10,240,000 floats
    // agg1 region reused after h is computed:
    float* agg2 = f;                          // N2*H
    float* h2   = f + (size_t)N2 * H;         // N2*H
    float* tbuf = f + (size_t)2 * N2 * H;     // N2*H

    int* ip = (int*)(f + (size_t)2 * N1 * H);
    int* cnt1    = ip;                  // N1
    int* cursor1 = ip + N1;             // N1
    int* cnt2    = ip + 2 * N1;         // N2
    int* cursor2 = ip + 2 * N1 + N2;    // N2
    int* rs1     = ip + 2 * N1 + 2 * N2;        // N1+1
    int* rs2     = rs1 + N1 + 1;                // N2+1
    int* eidx1   = rs2 + N2 + 1;                // E1
    int* eidx2   = eidx1 + E1;                  // E2

    // zero the four counter arrays (contiguous)
    hipMemsetAsync(ip, 0, (size_t)(2 * N1 + 2 * N2) * sizeof(int), stream);

    // ---- CSR build (both layers up front) ----
    count_k<<<(E1 + 255) / 256, 256, 0, stream>>>(dst1, cnt1, E1);
    count_k<<<(E2 + 255) / 256, 256, 0, stream>>>(dst2, cnt2, E2);
    exscan_k<<<1, 1024, 0, stream>>>(cnt1, rs1, N1);
    exscan_k<<<1, 1024, 0, stream>>>(cnt2, rs2, N2);
    fill_k<<<(E1 + 255) / 256, 256, 0, stream>>>(src1, dst1, rs1, cursor1, eidx1, E1);
    fill_k<<<(E2 + 255) / 256, 256, 0, stream>>>(src2, dst2, rs2, cursor2, eidx2, E2);

    // ---- layer 1 ----
    aggregate_k<<<N1, 128, 0, stream>>>(x, rs1, eidx1, agg1);
    {
        dim3 grid(H / 64, (N1 + 63) / 64);
        gemm_dual_k<<<grid, 256, 0, stream>>>(agg1, Wrel1, x, Wroot1, brel1, h,
                                              N1, H, H, 1);
    }

    // ---- layer 2 ----
    aggregate_k<<<N2, 128, 0, stream>>>(h, rs2, eidx2, agg2);
    {
        dim3 grid(H / 64, (N2 + 63) / 64);
        gemm_dual_k<<<grid, 256, 0, stream>>>(agg2, Wrel2, h, Wroot2, brel2, h2,
                                              N2, H, H, 0);
    }

    // ---- dense head ----
    {
        dim3 grid(H / 64, (N2 + 63) / 64);
        gemm_dual_k<<<grid, 256, 0, stream>>>(h2, Wlin, nullptr, nullptr, blin, tbuf,
                                              N2, H, H, 0);
    }
    head_k<<<(N2 * C + 255) / 256, 256, 0, stream>>>(tbuf, Whead, bhead, out, N2);
}

// Round 2
// 687.754 us; speedup vs baseline: 1.4278x; 1.4278x over previous
//
#include <hip/hip_runtime.h>
#include <hip/hip_bf16.h>
#include <cstdint>

// GCN: 2-layer GraphConv + dense head on MI355X.
// Round 2: bf16 MFMA GEMMs (16x16x32, 128x128 tile, BK=32, global_load_lds w=16,
// B pre-transposed to [N][K]), CSR aggregation emits bf16.

static constexpr int N1 = 20000;
static constexpr int N2 = 4000;
static constexpr int HH = 512;
static constexpr int C  = 10;
static constexpr int M1PAD = 20096;  // 157 * 128
static constexpr int M2PAD = 4096;   // 32 * 128

using frag  = __attribute__((ext_vector_type(8))) short;   // 8 bf16 (4 VGPRs)
using f32x4 = __attribute__((ext_vector_type(4))) float;   // 4 fp32 acc

__device__ inline float bf2f(unsigned short u) {
    unsigned t = ((unsigned)u) << 16; float f; __builtin_memcpy(&f, &t, 4); return f;
}
__device__ inline unsigned short f2bf(float f) {
    unsigned u; __builtin_memcpy(&u, &f, 4);
    u += 0x7FFFu + ((u >> 16) & 1u);  // RNE
    return (unsigned short)(u >> 16);
}

__device__ inline void gld16(const void* g, void* l) {
    __builtin_amdgcn_global_load_lds((const __attribute__((address_space(1))) void*)g,
                                     (__attribute__((address_space(3))) void*)l,
                                     16, 0, 0);
}

// ---------------- CSR build ----------------

__global__ void count_k(const int* __restrict__ dst, int* __restrict__ cnt, int E) {
    int g = blockIdx.x * 256 + threadIdx.x;
    if (g < E) atomicAdd(&cnt[dst[g]], 1);
}

__global__ __launch_bounds__(1024)
void exscan_k(const int* __restrict__ cnt, int* __restrict__ rs, int n) {
    __shared__ int part[1024];
    int t = threadIdx.x;
    int chunk = (n + 1023) >> 10;
    int b = t * chunk;
    int e = min(b + chunk, n);
    int s = 0;
    for (int i = b; i < e; ++i) s += cnt[i];
    part[t] = s;
    __syncthreads();
    for (int off = 1; off < 1024; off <<= 1) {
        int add = (t >= off) ? part[t - off] : 0;
        __syncthreads();
        part[t] += add;
        __syncthreads();
    }
    int base = (t == 0) ? 0 : part[t - 1];
    for (int i = b; i < e; ++i) { rs[i] = base; base += cnt[i]; }
    if (t == 1023) rs[n] = part[1023];
}

__global__ void fill_k(const int* __restrict__ src, const int* __restrict__ dst,
                       const int* __restrict__ rs, int* __restrict__ cursor,
                       int* __restrict__ eidx, int E) {
    int g = blockIdx.x * 256 + threadIdx.x;
    if (g < E) {
        int d = dst[g];
        int pos = atomicAdd(&cursor[d], 1);
        eidx[rs[d] + pos] = src[g];
    }
}

// ---------------- casts ----------------

// x[:N1] fp32 -> bf16, 8 elems/thread
__global__ void castx_k(const float* __restrict__ x, unsigned short* __restrict__ o, int n8) {
    int g = blockIdx.x * 256 + threadIdx.x;
    if (g >= n8) return;
    const float4* p = (const float4*)x + (size_t)g * 2;
    float4 a = p[0], b = p[1];
    unsigned short t[8] = {f2bf(a.x), f2bf(a.y), f2bf(a.z), f2bf(a.w),
                           f2bf(b.x), f2bf(b.y), f2bf(b.z), f2bf(b.w)};
    *(uint4*)(o + (size_t)g * 8) = *(const uint4*)t;
}

// transpose + cast 512x512 weights -> bf16 [N][K]; 5 weights packed
__global__ __launch_bounds__(256)
void castw_k(const float* W0, const float* W1, const float* W2, const float* W3,
             const float* W4, unsigned short* __restrict__ out) {
    const float* Ws[5] = {W0, W1, W2, W3, W4};
    const float* W = Ws[blockIdx.z];
    unsigned short* O = out + (size_t)blockIdx.z * HH * HH;
    __shared__ float t[32][33];
    int bx = blockIdx.x * 32;  // n
    int by = blockIdx.y * 32;  // k
    int tx = threadIdx.x & 31, ty = threadIdx.x >> 5;  // 32 x 8
#pragma unroll
    for (int i = 0; i < 4; ++i)
        t[ty + i * 8][tx] = W[(size_t)(by + ty + i * 8) * HH + bx + tx];
    __syncthreads();
#pragma unroll
    for (int i = 0; i < 4; ++i)
        O[(size_t)(bx + ty + i * 8) * HH + by + tx] = f2bf(t[tx][ty + i * 8]);
}

// ---------------- aggregation: one wave per target node ----------------

__global__ __launch_bounds__(64)
void agg_f32_k(const float* __restrict__ x, const int* __restrict__ rs,
               const int* __restrict__ eidx, unsigned short* __restrict__ out) {
    int node = blockIdx.x;
    int l = threadIdx.x;  // 0..63, elems l*8 .. l*8+7
    int s = rs[node], e = rs[node + 1];
    float acc[8] = {};
    int i = s;
    for (; i + 2 <= e; i += 2) {
        const float* p0 = x + (size_t)eidx[i] * HH + l * 8;
        const float* p1 = x + (size_t)eidx[i + 1] * HH + l * 8;
        float4 a = *(const float4*)p0, a2 = *(const float4*)(p0 + 4);
        float4 b = *(const float4*)p1, b2 = *(const float4*)(p1 + 4);
        acc[0] += a.x + b.x;  acc[1] += a.y + b.y;
        acc[2] += a.z + b.z;  acc[3] += a.w + b.w;
        acc[4] += a2.x + b2.x; acc[5] += a2.y + b2.y;
        acc[6] += a2.z + b2.z; acc[7] += a2.w + b2.w;
    }
    if (i < e) {
        const float* p0 = x + (size_t)eidx[i] * HH + l * 8;
        float4 a = *(const float4*)p0, a2 = *(const float4*)(p0 + 4);
        acc[0] += a.x; acc[1] += a.y; acc[2] += a.z; acc[3] += a.w;
        acc[4] += a2.x; acc[5] += a2.y; acc[6] += a2.z; acc[7] += a2.w;
    }
    unsigned short o[8];
#pragma unroll
    for (int j = 0; j < 8; ++j) o[j] = f2bf(acc[j]);
    *(uint4*)(out + (size_t)node * HH + l * 8) = *(const uint4*)o;
}

__global__ __launch_bounds__(64)
void agg_bf16_k(const unsigned short* __restrict__ x, const int* __restrict__ rs,
                const int* __restrict__ eidx, unsigned short* __restrict__ out) {
    int node = blockIdx.x;
    int l = threadIdx.x;
    int s = rs[node], e = rs[node + 1];
    float acc[8] = {};
    int i = s;
    for (; i + 2 <= e; i += 2) {
        uint4 a = *(const uint4*)(x + (size_t)eidx[i] * HH + l * 8);
        uint4 b = *(const uint4*)(x + (size_t)eidx[i + 1] * HH + l * 8);
        const unsigned short* pa = (const unsigned short*)&a;
        const unsigned short* pb = (const unsigned short*)&b;
#pragma unroll
        for (int j = 0; j < 8; ++j) acc[j] += bf2f(pa[j]) + bf2f(pb[j]);
    }
    if (i < e) {
        uint4 a = *(const uint4*)(x + (size_t)eidx[i] * HH + l * 8);
        const unsigned short* pa = (const unsigned short*)&a;
#pragma unroll
        for (int j = 0; j < 8; ++j) acc[j] += bf2f(pa[j]);
    }
    unsigned short o[8];
#pragma unroll
    for (int j = 0; j < 8; ++j) o[j] = f2bf(acc[j]);
    *(uint4*)(out + (size_t)node * HH + l * 8) = *(const uint4*)o;
}

// ---------------- bf16 MFMA GEMM ----------------
// C[M,512] = sum_p A_p[Mpad,512] @ B_p^T  (+ bias, opt relu)
// A row-major bf16 stride 512; Bt row-major [512 n][512 k] bf16.
// Block 256 thr = 4 waves, tile 128x128, BK=32. Wave (wr,wc) -> 64x64 subtile.
template <int OUT_BF16, int RELU, int DUAL>
__global__ __launch_bounds__(256)
void gemm_mfma_k(const short* __restrict__ A1, const short* __restrict__ B1t,
                 const short* __restrict__ A2, const short* __restrict__ B2t,
                 const float* __restrict__ bias, void* __restrict__ Cout, int M) {
    __shared__ __align__(16) short As[128 * 32];
    __shared__ __align__(16) short Bs[128 * 32];
    const int bn = blockIdx.x * 128;
    const int bm = blockIdx.y * 128;
    const int tid = threadIdx.x;
    const int lane = tid & 63;
    const int wave = tid >> 6;
    const int l15 = lane & 15;
    const int quad = lane >> 4;
    const int wm = (wave >> 1) * 64;
    const int wn = (wave & 1) * 64;

    // staging map: idx in [0,512): row = idx>>2 (0..127), seg = idx&3 (16B each)
    const int r0 = tid >> 2;
    const int sg = (tid & 3) * 8;  // bf16 offset within the 32-k row

    f32x4 acc[4][4] = {};

    for (int pass = 0; pass < (DUAL ? 2 : 1); ++pass) {
        const short* A  = pass ? A2 : A1;
        const short* Bt = pass ? B2t : B1t;
        for (int k0 = 0; k0 < 512; k0 += 32) {
            gld16(A + (size_t)(bm + r0) * 512 + k0 + sg, As + tid * 8);
            gld16(A + (size_t)(bm + r0 + 64) * 512 + k0 + sg, As + (tid + 256) * 8);
            gld16(Bt + (size_t)(bn + r0) * 512 + k0 + sg, Bs + tid * 8);
            gld16(Bt + (size_t)(bn + r0 + 64) * 512 + k0 + sg, Bs + (tid + 256) * 8);
            __syncthreads();
            frag a[4], b[4];
#pragma unroll
            for (int mi = 0; mi < 4; ++mi)
                a[mi] = *(const frag*)(As + (wm + mi * 16 + l15) * 32 + quad * 8);
#pragma unroll
            for (int ni = 0; ni < 4; ++ni)
                b[ni] = *(const frag*)(Bs + (wn + ni * 16 + l15) * 32 + quad * 8);
#pragma unroll
            for (int mi = 0; mi < 4; ++mi)
#pragma unroll
                for (int ni = 0; ni < 4; ++ni)
                    acc[mi][ni] = __builtin_amdgcn_mfma_f32_16x16x32_bf16(
                        a[mi], b[ni], acc[mi][ni], 0, 0, 0);
            __syncthreads();
        }
    }

#pragma unroll
    for (int ni = 0; ni < 4; ++ni) {
        const int gn = bn + wn + ni * 16 + l15;
        const float bv = bias[gn];
#pragma unroll
        for (int mi = 0; mi < 4; ++mi) {
            const int gm0 = bm + wm + mi * 16 + quad * 4;
#pragma unroll
            for (int r = 0; r < 4; ++r) {
                const int gm = gm0 + r;
                if (gm < M) {
                    float v = acc[mi][ni][r] + bv;
                    if (RELU) v = fmaxf(v, 0.f);
                    if (OUT_BF16)
                        ((unsigned short*)Cout)[(size_t)gm * 512 + gn] = f2bf(v);
                    else
                        ((float*)Cout)[(size_t)gm * 512 + gn] = v;
                }
            }
        }
    }
}

// ---------------- head ----------------
__global__ void head_k(const float* __restrict__ T, const float* __restrict__ Wh,
                       const float* __restrict__ bh, float* __restrict__ out, int M) {
    int g = blockIdx.x * 256 + threadIdx.x;
    if (g >= M * C) return;
    int m = g / C, c = g % C;
    float acc = bh[c];
    const float* row = T + (size_t)m * HH;
#pragma unroll 4
    for (int k = 0; k < HH; ++k) acc += row[k] * Wh[k * C + c];
    out[g] = acc;
}

extern "C" void kernel_launch(void* const* d_in, const int* in_sizes, int n_in,
                              void* d_out, int out_size, void* d_ws, size_t ws_size,
                              hipStream_t stream) {
    const float* x      = (const float*)d_in[0];
    const int*   src1   = (const int*)d_in[1];
    const int*   dst1   = (const int*)d_in[2];
    const int*   src2   = (const int*)d_in[3];
    const int*   dst2   = (const int*)d_in[4];
    const float* Wrel1  = (const float*)d_in[5];
    const float* brel1  = (const float*)d_in[6];
    const float* Wroot1 = (const float*)d_in[7];
    const float* Wrel2  = (const float*)d_in[8];
    const float* brel2  = (const float*)d_in[9];
    const float* Wroot2 = (const float*)d_in[10];
    const float* Wlin   = (const float*)d_in[11];
    const float* blin   = (const float*)d_in[12];
    const float* Whead  = (const float*)d_in[13];
    const float* bhead  = (const float*)d_in[14];
    float* out = (float*)d_out;

    const int E1 = in_sizes[1];
    const int E2 = in_sizes[3];

    // ---- workspace layout (≈84 MB) ----
    char* w = (char*)d_ws;
    auto alloc = [&](size_t bytes) { char* p = w; w += (bytes + 255) & ~(size_t)255; return p; };
    unsigned short* agg1b = (unsigned short*)alloc((size_t)M1PAD * HH * 2);
    unsigned short* xb1   = (unsigned short*)alloc((size_t)M1PAD * HH * 2);
    unsigned short* hb    = (unsigned short*)alloc((size_t)M1PAD * HH * 2);
    unsigned short* agg2b = (unsigned short*)alloc((size_t)M2PAD * HH * 2);
    unsigned short* h2b   = (unsigned short*)alloc((size_t)M2PAD * HH * 2);
    float*          tbuf  = (float*)alloc((size_t)M2PAD * HH * 4);
    unsigned short* Wt    = (unsigned short*)alloc((size_t)5 * HH * HH * 2);
    int* ip = (int*)alloc((size_t)(2 * N1 + 2 * N2 + (N1 + 1) + (N2 + 1) + 600000) * 4);
    int* cnt1    = ip;
    int* cursor1 = ip + N1;
    int* cnt2    = ip + 2 * N1;
    int* cursor2 = ip + 2 * N1 + N2;
    int* rs1     = ip + 2 * N1 + 2 * N2;
    int* rs2     = rs1 + N1 + 1;
    int* eidx1   = rs2 + N2 + 1;
    int* eidx2   = eidx1 + E1;

    const short* Wrel1t  = (const short*)(Wt + 0 * (size_t)HH * HH);
    const short* Wroot1t = (const short*)(Wt + 1 * (size_t)HH * HH);
    const short* Wrel2t  = (const short*)(Wt + 2 * (size_t)HH * HH);
    const short* Wroot2t = (const short*)(Wt + 3 * (size_t)HH * HH);
    const short* Wlint   = (const short*)(Wt + 4 * (size_t)HH * HH);

    hipMemsetAsync(ip, 0, (size_t)(2 * N1 + 2 * N2) * sizeof(int), stream);

    // ---- CSR build ----
    count_k<<<(E1 + 255) / 256, 256, 0, stream>>>(dst1, cnt1, E1);
    count_k<<<(E2 + 255) / 256, 256, 0, stream>>>(dst2, cnt2, E2);
    exscan_k<<<1, 1024, 0, stream>>>(cnt1, rs1, N1);
    exscan_k<<<1, 1024, 0, stream>>>(cnt2, rs2, N2);
    fill_k<<<(E1 + 255) / 256, 256, 0, stream>>>(src1, dst1, rs1, cursor1, eidx1, E1);
    fill_k<<<(E2 + 255) / 256, 256, 0, stream>>>(src2, dst2, rs2, cursor2, eidx2, E2);

    // ---- casts ----
    castx_k<<<(N1 * HH / 8 + 255) / 256, 256, 0, stream>>>(x, xb1, N1 * HH / 8);
    {
        dim3 grid(HH / 32, HH / 32, 5);
        castw_k<<<grid, 256, 0, stream>>>(Wrel1, Wroot1, Wrel2, Wroot2, Wlin, Wt);
    }

    // ---- layer 1 ----
    agg_f32_k<<<N1, 64, 0, stream>>>(x, rs1, eidx1, agg1b);
    {
        dim3 grid(HH / 128, M1PAD / 128);
        gemm_mfma_k<1, 1, 1><<<grid, 256, 0, stream>>>(
            (const short*)agg1b, Wrel1t, (const short*)xb1, Wroot1t, brel1, hb, N1);
    }

    // ---- layer 2 ----
    agg_bf16_k<<<N2, 64, 0, stream>>>(hb, rs2, eidx2, agg2b);
    {
        dim3 grid(HH / 128, M2PAD / 128);
        gemm_mfma_k<1, 0, 1><<<grid, 256, 0, stream>>>(
            (const short*)agg2b, Wrel2t, (const short*)hb, Wroot2t, brel2, h2b, N2);
    }

    // ---- dense head ----
    {
        dim3 grid(HH / 128, M2PAD / 128);
        gemm_mfma_k<0, 0, 0><<<grid, 256, 0, stream>>>(
            (const short*)h2b, Wlint, nullptr, nullptr, blin, tbuf, N2);
    }
    head_k<<<(N2 * C + 255) / 256, 256, 0, stream>>>(tbuf, Whead, bhead, out, N2);
}

// Round 3
// 678.242 us; speedup vs baseline: 1.4479x; 1.0140x over previous
//
#include <hip/hip_runtime.h>
#include <hip/hip_bf16.h>
#include <cstdint>

// GCN: 2-layer GraphConv + dense head on MI355X. Round 3:
//  - full-x bf16 cast (102 MB, L3-resident) + bf16 gather (ws_size-branched)
//  - tail fused algebraically: out = agg2@W2a + h[:N2]@W2b + bout where
//    W2a=Wrel2@Wlin@Whead, W2b=Wroot2@Wlin@Whead (precomputed, [10][512] fp32)
//  - CSR build merged into 3 dispatches for both layers

static constexpr int N0 = 100000;
static constexpr int N1 = 20000;
static constexpr int N2 = 4000;
static constexpr int HH = 512;
static constexpr int C  = 10;
static constexpr int M1PAD = 20096;  // 157 * 128

using frag  = __attribute__((ext_vector_type(8))) short;
using f32x4 = __attribute__((ext_vector_type(4))) float;

__device__ inline float bf2f(unsigned short u) {
    unsigned t = ((unsigned)u) << 16; float f; __builtin_memcpy(&f, &t, 4); return f;
}
__device__ inline unsigned short f2bf(float f) {
    unsigned u; __builtin_memcpy(&u, &f, 4);
    u += 0x7FFFu + ((u >> 16) & 1u);  // RNE
    return (unsigned short)(u >> 16);
}
__device__ inline void gld16(const void* g, void* l) {
    __builtin_amdgcn_global_load_lds((const __attribute__((address_space(1))) void*)g,
                                     (__attribute__((address_space(3))) void*)l,
                                     16, 0, 0);
}

// ---------------- CSR build (merged) ----------------

__global__ void count_both_k(const int* __restrict__ dst1, const int* __restrict__ dst2,
                             int* __restrict__ cnt1, int* __restrict__ cnt2,
                             int E1, int E2) {
    int g = blockIdx.x * 256 + threadIdx.x;
    if (g < E1) atomicAdd(&cnt1[dst1[g]], 1);
    else if (g < E1 + E2) atomicAdd(&cnt2[dst2[g - E1]], 1);
}

__global__ __launch_bounds__(1024)
void exscan2_k(const int* __restrict__ cnt1, int* __restrict__ rs1, int n1,
               const int* __restrict__ cnt2, int* __restrict__ rs2, int n2) {
    const int* cnt = blockIdx.x ? cnt2 : cnt1;
    int* rs = blockIdx.x ? rs2 : rs1;
    int n = blockIdx.x ? n2 : n1;
    __shared__ int part[1024];
    int t = threadIdx.x;
    int chunk = (n + 1023) >> 10;
    int b = t * chunk;
    int e = min(b + chunk, n);
    int s = 0;
    for (int i = b; i < e; ++i) s += cnt[i];
    part[t] = s;
    __syncthreads();
    for (int off = 1; off < 1024; off <<= 1) {
        int add = (t >= off) ? part[t - off] : 0;
        __syncthreads();
        part[t] += add;
        __syncthreads();
    }
    int base = (t == 0) ? 0 : part[t - 1];
    for (int i = b; i < e; ++i) { rs[i] = base; base += cnt[i]; }
    if (t == 1023) rs[n] = part[1023];
}

__global__ void fill_both_k(const int* __restrict__ src1, const int* __restrict__ dst1,
                            const int* __restrict__ src2, const int* __restrict__ dst2,
                            const int* __restrict__ rs1, const int* __restrict__ rs2,
                            int* __restrict__ cur1, int* __restrict__ cur2,
                            int* __restrict__ eidx1, int* __restrict__ eidx2,
                            int E1, int E2) {
    int g = blockIdx.x * 256 + threadIdx.x;
    if (g < E1) {
        int d = dst1[g];
        int pos = atomicAdd(&cur1[d], 1);
        eidx1[rs1[d] + pos] = src1[g];
    } else if (g < E1 + E2) {
        int gg = g - E1;
        int d = dst2[gg];
        int pos = atomicAdd(&cur2[d], 1);
        eidx2[rs2[d] + pos] = src2[gg];
    }
}

// ---------------- casts ----------------

__global__ void castx_k(const float* __restrict__ x, unsigned short* __restrict__ o, int n8) {
    int g = blockIdx.x * 256 + threadIdx.x;
    if (g >= n8) return;
    const float4* p = (const float4*)x + (size_t)g * 2;
    float4 a = p[0], b = p[1];
    unsigned short t[8] = {f2bf(a.x), f2bf(a.y), f2bf(a.z), f2bf(a.w),
                           f2bf(b.x), f2bf(b.y), f2bf(b.z), f2bf(b.w)};
    *(uint4*)(o + (size_t)g * 8) = *(const uint4*)t;
}

// transpose + cast 512x512 weights -> bf16 [N][K]; 2 weights (z index)
__global__ __launch_bounds__(256)
void castw_k(const float* W0, const float* W1, unsigned short* __restrict__ out) {
    const float* W = blockIdx.z ? W1 : W0;
    unsigned short* O = out + (size_t)blockIdx.z * HH * HH;
    __shared__ float t[32][33];
    int bx = blockIdx.x * 32;  // n
    int by = blockIdx.y * 32;  // k
    int tx = threadIdx.x & 31, ty = threadIdx.x >> 5;
#pragma unroll
    for (int i = 0; i < 4; ++i)
        t[ty + i * 8][tx] = W[(size_t)(by + ty + i * 8) * HH + bx + tx];
    __syncthreads();
#pragma unroll
    for (int i = 0; i < 4; ++i)
        O[(size_t)(bx + ty + i * 8) * HH + by + tx] = f2bf(t[tx][ty + i * 8]);
}

// ---------------- tail weight products ----------------
// P1[k][c] = sum_j Wlin[k][j] * Whead[j][c]          (fp32 [512][10])
__global__ void p1_k(const float* __restrict__ Wlin, const float* __restrict__ Whead,
                     float* __restrict__ P1) {
    int g = blockIdx.x * 256 + threadIdx.x;
    if (g >= HH * C) return;
    int k = g / C, c = g % C;
    float acc = 0.f;
    const float* row = Wlin + (size_t)k * HH;
#pragma unroll 4
    for (int j = 0; j < HH; ++j) acc += row[j] * Whead[j * C + c];
    P1[g] = acc;
}

// z=0: W2aT[c][k] = sum_j Wrel2[k][j]*P1[j][c]; z=1 with Wroot2 -> W2bT
// block (0,0,0) threads 0..9 also compute bout.
__global__ void w2ab_k(const float* __restrict__ Wrel2, const float* __restrict__ Wroot2,
                       const float* __restrict__ P1,
                       const float* __restrict__ brel2, const float* __restrict__ blin,
                       const float* __restrict__ Whead, const float* __restrict__ bhead,
                       float* __restrict__ W2aT, float* __restrict__ W2bT,
                       float* __restrict__ bout) {
    const float* W = blockIdx.z ? Wroot2 : Wrel2;
    float* O = blockIdx.z ? W2bT : W2aT;
    int g = blockIdx.x * 256 + threadIdx.x;
    if (g < HH * C) {
        int k = g / C, c = g % C;
        float acc = 0.f;
        const float* row = W + (size_t)k * HH;
#pragma unroll 4
        for (int j = 0; j < HH; ++j) acc += row[j] * P1[j * C + c];
        O[c * HH + k] = acc;   // transposed store [10][512]
    }
    if (blockIdx.z == 0 && blockIdx.x == 0 && threadIdx.x < C) {
        int c = threadIdx.x;
        float acc = bhead[c];
        for (int j = 0; j < HH; ++j)
            acc += brel2[j] * P1[j * C + c] + blin[j] * Whead[j * C + c];
        bout[c] = acc;
    }
}

// ---------------- aggregation: one wave per node, 4 waves/block ----------------

__global__ __launch_bounds__(256)
void agg_bf16_k(const unsigned short* __restrict__ x, const int* __restrict__ rs,
                const int* __restrict__ eidx, unsigned short* __restrict__ out, int n) {
    int node = blockIdx.x * 4 + (threadIdx.x >> 6);
    if (node >= n) return;
    int l = threadIdx.x & 63;
    int s = rs[node], e = rs[node + 1];
    float acc[8] = {};
    int i = s;
    for (; i + 4 <= e; i += 4) {
        uint4 a = *(const uint4*)(x + (size_t)eidx[i]     * HH + l * 8);
        uint4 b = *(const uint4*)(x + (size_t)eidx[i + 1] * HH + l * 8);
        uint4 c = *(const uint4*)(x + (size_t)eidx[i + 2] * HH + l * 8);
        uint4 d = *(const uint4*)(x + (size_t)eidx[i + 3] * HH + l * 8);
        const unsigned short* pa = (const unsigned short*)&a;
        const unsigned short* pb = (const unsigned short*)&b;
        const unsigned short* pc = (const unsigned short*)&c;
        const unsigned short* pd = (const unsigned short*)&d;
#pragma unroll
        for (int j = 0; j < 8; ++j)
            acc[j] += (bf2f(pa[j]) + bf2f(pb[j])) + (bf2f(pc[j]) + bf2f(pd[j]));
    }
    for (; i < e; ++i) {
        uint4 a = *(const uint4*)(x + (size_t)eidx[i] * HH + l * 8);
        const unsigned short* pa = (const unsigned short*)&a;
#pragma unroll
        for (int j = 0; j < 8; ++j) acc[j] += bf2f(pa[j]);
    }
    unsigned short o[8];
#pragma unroll
    for (int j = 0; j < 8; ++j) o[j] = f2bf(acc[j]);
    *(uint4*)(out + (size_t)node * HH + l * 8) = *(const uint4*)o;
}

__global__ __launch_bounds__(256)
void agg_f32_k(const float* __restrict__ x, const int* __restrict__ rs,
               const int* __restrict__ eidx, unsigned short* __restrict__ out, int n) {
    int node = blockIdx.x * 4 + (threadIdx.x >> 6);
    if (node >= n) return;
    int l = threadIdx.x & 63;
    int s = rs[node], e = rs[node + 1];
    float acc[8] = {};
    int i = s;
    for (; i + 2 <= e; i += 2) {
        const float* p0 = x + (size_t)eidx[i] * HH + l * 8;
        const float* p1 = x + (size_t)eidx[i + 1] * HH + l * 8;
        float4 a = *(const float4*)p0, a2 = *(const float4*)(p0 + 4);
        float4 b = *(const float4*)p1, b2 = *(const float4*)(p1 + 4);
        acc[0] += a.x + b.x;  acc[1] += a.y + b.y;
        acc[2] += a.z + b.z;  acc[3] += a.w + b.w;
        acc[4] += a2.x + b2.x; acc[5] += a2.y + b2.y;
        acc[6] += a2.z + b2.z; acc[7] += a2.w + b2.w;
    }
    if (i < e) {
        const float* p0 = x + (size_t)eidx[i] * HH + l * 8;
        float4 a = *(const float4*)p0, a2 = *(const float4*)(p0 + 4);
        acc[0] += a.x; acc[1] += a.y; acc[2] += a.z; acc[3] += a.w;
        acc[4] += a2.x; acc[5] += a2.y; acc[6] += a2.z; acc[7] += a2.w;
    }
    unsigned short o[8];
#pragma unroll
    for (int j = 0; j < 8; ++j) o[j] = f2bf(acc[j]);
    *(uint4*)(out + (size_t)node * HH + l * 8) = *(const uint4*)o;
}

// ---------------- bf16 MFMA GEMM (layer 1) ----------------
__global__ __launch_bounds__(256)
void gemm_mfma_k(const short* __restrict__ A1, const short* __restrict__ B1t,
                 const short* __restrict__ A2, const short* __restrict__ B2t,
                 const float* __restrict__ bias, unsigned short* __restrict__ Cout, int M) {
    __shared__ __align__(16) short As[128 * 32];
    __shared__ __align__(16) short Bs[128 * 32];
    const int bn = blockIdx.x * 128;
    const int bm = blockIdx.y * 128;
    const int tid = threadIdx.x;
    const int lane = tid & 63;
    const int wave = tid >> 6;
    const int l15 = lane & 15;
    const int quad = lane >> 4;
    const int wm = (wave >> 1) * 64;
    const int wn = (wave & 1) * 64;
    const int r0 = tid >> 2;
    const int sg = (tid & 3) * 8;

    f32x4 acc[4][4] = {};

    for (int pass = 0; pass < 2; ++pass) {
        const short* A  = pass ? A2 : A1;
        const short* Bt = pass ? B2t : B1t;
        for (int k0 = 0; k0 < 512; k0 += 32) {
            gld16(A + (size_t)(bm + r0) * 512 + k0 + sg, As + tid * 8);
            gld16(A + (size_t)(bm + r0 + 64) * 512 + k0 + sg, As + (tid + 256) * 8);
            gld16(Bt + (size_t)(bn + r0) * 512 + k0 + sg, Bs + tid * 8);
            gld16(Bt + (size_t)(bn + r0 + 64) * 512 + k0 + sg, Bs + (tid + 256) * 8);
            __syncthreads();
            frag a[4], b[4];
#pragma unroll
            for (int mi = 0; mi < 4; ++mi)
                a[mi] = *(const frag*)(As + (wm + mi * 16 + l15) * 32 + quad * 8);
#pragma unroll
            for (int ni = 0; ni < 4; ++ni)
                b[ni] = *(const frag*)(Bs + (wn + ni * 16 + l15) * 32 + quad * 8);
#pragma unroll
            for (int mi = 0; mi < 4; ++mi)
#pragma unroll
                for (int ni = 0; ni < 4; ++ni)
                    acc[mi][ni] = __builtin_amdgcn_mfma_f32_16x16x32_bf16(
                        a[mi], b[ni], acc[mi][ni], 0, 0, 0);
            __syncthreads();
        }
    }

#pragma unroll
    for (int ni = 0; ni < 4; ++ni) {
        const int gn = bn + wn + ni * 16 + l15;
        const float bv = bias[gn];
#pragma unroll
        for (int mi = 0; mi < 4; ++mi) {
            const int gm0 = bm + wm + mi * 16 + quad * 4;
#pragma unroll
            for (int r = 0; r < 4; ++r) {
                const int gm = gm0 + r;
                if (gm < M) {
                    float v = fmaxf(acc[mi][ni][r] + bv, 0.f);
                    Cout[(size_t)gm * 512 + gn] = f2bf(v);
                }
            }
        }
    }
}

// ---------------- fused tail: gather + [512,10] matvec -> out ----------------
__global__ __launch_bounds__(256)
void tail_k(const unsigned short* __restrict__ h, const int* __restrict__ rs,
            const int* __restrict__ eidx,
            const float* __restrict__ W2aT, const float* __restrict__ W2bT,
            const float* __restrict__ bout, float* __restrict__ out) {
    int node = blockIdx.x * 4 + (threadIdx.x >> 6);
    if (node >= N2) return;
    int l = threadIdx.x & 63;
    int s = rs[node], e = rs[node + 1];
    float acc[8] = {};
    int i = s;
    for (; i + 2 <= e; i += 2) {
        uint4 a = *(const uint4*)(h + (size_t)eidx[i]     * HH + l * 8);
        uint4 b = *(const uint4*)(h + (size_t)eidx[i + 1] * HH + l * 8);
        const unsigned short* pa = (const unsigned short*)&a;
        const unsigned short* pb = (const unsigned short*)&b;
#pragma unroll
        for (int j = 0; j < 8; ++j) acc[j] += bf2f(pa[j]) + bf2f(pb[j]);
    }
    if (i < e) {
        uint4 a = *(const uint4*)(h + (size_t)eidx[i] * HH + l * 8);
        const unsigned short* pa = (const unsigned short*)&a;
#pragma unroll
        for (int j = 0; j < 8; ++j) acc[j] += bf2f(pa[j]);
    }
    float r[8];
    {
        uint4 a = *(const uint4*)(h + (size_t)node * HH + l * 8);
        const unsigned short* pa = (const unsigned short*)&a;
#pragma unroll
        for (int j = 0; j < 8; ++j) r[j] = bf2f(pa[j]);
    }
    float p[C];
#pragma unroll
    for (int c = 0; c < C; ++c) {
        const float* wa = W2aT + c * HH + l * 8;
        const float* wb = W2bT + c * HH + l * 8;
        float4 wa0 = *(const float4*)wa, wa1 = *(const float4*)(wa + 4);
        float4 wb0 = *(const float4*)wb, wb1 = *(const float4*)(wb + 4);
        float v = acc[0] * wa0.x + acc[1] * wa0.y + acc[2] * wa0.z + acc[3] * wa0.w
                + acc[4] * wa1.x + acc[5] * wa1.y + acc[6] * wa1.z + acc[7] * wa1.w
                + r[0] * wb0.x + r[1] * wb0.y + r[2] * wb0.z + r[3] * wb0.w
                + r[4] * wb1.x + r[5] * wb1.y + r[6] * wb1.z + r[7] * wb1.w;
#pragma unroll
        for (int off = 32; off; off >>= 1) v += __shfl_xor(v, off);
        p[c] = v;
    }
    if (l == 0) {
#pragma unroll
        for (int c = 0; c < C; ++c) out[(size_t)node * C + c] = p[c] + bout[c];
    }
}

extern "C" void kernel_launch(void* const* d_in, const int* in_sizes, int n_in,
                              void* d_out, int out_size, void* d_ws, size_t ws_size,
                              hipStream_t stream) {
    const float* x      = (const float*)d_in[0];
    const int*   src1   = (const int*)d_in[1];
    const int*   dst1   = (const int*)d_in[2];
    const int*   src2   = (const int*)d_in[3];
    const int*   dst2   = (const int*)d_in[4];
    const float* Wrel1  = (const float*)d_in[5];
    const float* brel1  = (const float*)d_in[6];
    const float* Wroot1 = (const float*)d_in[7];
    const float* Wrel2  = (const float*)d_in[8];
    const float* brel2  = (const float*)d_in[9];
    const float* Wroot2 = (const float*)d_in[10];
    const float* Wlin   = (const float*)d_in[11];
    const float* blin   = (const float*)d_in[12];
    const float* Whead  = (const float*)d_in[13];
    const float* bhead  = (const float*)d_in[14];
    float* out = (float*)d_out;

    const int E1 = in_sizes[1];
    const int E2 = in_sizes[3];

    // ---- workspace layout ----
    char* w = (char*)d_ws;
    auto alloc = [&](size_t bytes) { char* p = w; w += (bytes + 255) & ~(size_t)255; return p; };

    const size_t xb_full_bytes = (size_t)N0 * HH * 2;       // 102.4 MB
    const size_t xb_n1_bytes   = (size_t)M1PAD * HH * 2;    // 20.6 MB
    const size_t fixed_bytes =
        2 * (size_t)M1PAD * HH * 2 +           // agg1b + hb
        2 * (size_t)HH * HH * 2 +              // Wt (2 weights)
        ((size_t)HH * C * 4) * 3 +             // P1, W2aT, W2bT
        256 +                                  // bout
        ((size_t)2 * N1 + 2 * N2 + N1 + 1 + N2 + 1 + 700000) * 4 + 16 * 256;
    const bool full_x = ws_size >= fixed_bytes + xb_full_bytes;

    unsigned short* xb    = (unsigned short*)alloc(full_x ? xb_full_bytes : xb_n1_bytes);
    unsigned short* agg1b = (unsigned short*)alloc((size_t)M1PAD * HH * 2);
    unsigned short* hb    = (unsigned short*)alloc((size_t)M1PAD * HH * 2);
    unsigned short* Wt    = (unsigned short*)alloc((size_t)2 * HH * HH * 2);
    float* P1   = (float*)alloc((size_t)HH * C * 4);
    float* W2aT = (float*)alloc((size_t)HH * C * 4);
    float* W2bT = (float*)alloc((size_t)HH * C * 4);
    float* boutp = (float*)alloc(256);
    int* ip = (int*)alloc((size_t)(2 * N1 + 2 * N2 + (N1 + 1) + (N2 + 1) + E1 + E2) * 4);
    int* cnt1    = ip;
    int* cur1    = ip + N1;
    int* cnt2    = ip + 2 * N1;
    int* cur2    = ip + 2 * N1 + N2;
    int* rs1     = ip + 2 * N1 + 2 * N2;
    int* rs2     = rs1 + N1 + 1;
    int* eidx1   = rs2 + N2 + 1;
    int* eidx2   = eidx1 + E1;

    const short* Wrel1t  = (const short*)(Wt);
    const short* Wroot1t = (const short*)(Wt + (size_t)HH * HH);

    hipMemsetAsync(ip, 0, (size_t)(2 * N1 + 2 * N2) * sizeof(int), stream);

    // ---- CSR build (both layers, merged) ----
    count_both_k<<<(E1 + E2 + 255) / 256, 256, 0, stream>>>(dst1, dst2, cnt1, cnt2, E1, E2);
    exscan2_k<<<2, 1024, 0, stream>>>(cnt1, rs1, N1, cnt2, rs2, N2);
    fill_both_k<<<(E1 + E2 + 255) / 256, 256, 0, stream>>>(
        src1, dst1, src2, dst2, rs1, rs2, cur1, cur2, eidx1, eidx2, E1, E2);

    // ---- casts & weight products ----
    {
        int nrows = full_x ? N0 : N1;
        castx_k<<<(nrows * HH / 8 + 255) / 256, 256, 0, stream>>>(x, xb, nrows * HH / 8);
    }
    {
        dim3 grid(HH / 32, HH / 32, 2);
        castw_k<<<grid, 256, 0, stream>>>(Wrel1, Wroot1, Wt);
    }
    p1_k<<<(HH * C + 255) / 256, 256, 0, stream>>>(Wlin, Whead, P1);
    {
        dim3 grid((HH * C + 255) / 256, 1, 2);
        w2ab_k<<<grid, 256, 0, stream>>>(Wrel2, Wroot2, P1, brel2, blin, Whead, bhead,
                                         W2aT, W2bT, boutp);
    }

    // ---- layer 1: aggregate + GEMM ----
    if (full_x)
        agg_bf16_k<<<(N1 + 3) / 4, 256, 0, stream>>>(xb, rs1, eidx1, agg1b, N1);
    else
        agg_f32_k<<<(N1 + 3) / 4, 256, 0, stream>>>(x, rs1, eidx1, agg1b, N1);
    {
        dim3 grid(HH / 128, M1PAD / 128);
        gemm_mfma_k<<<grid, 256, 0, stream>>>(
            (const short*)agg1b, Wrel1t, (const short*)xb, Wroot1t, brel1, hb, N1);
    }

    // ---- fused layer 2 + head ----
    tail_k<<<(N2 + 3) / 4, 256, 0, stream>>>(hb, rs2, eidx2, W2aT, W2bT, boutp, out);
}

// Round 4
// 636.705 us; speedup vs baseline: 1.5423x; 1.0652x over previous
//
#include <hip/hip_runtime.h>
#include <hip/hip_bf16.h>
#include <cstdint>

// GCN: 2-layer GraphConv + dense head on MI355X. Round 4:
//  - merged prep kernels: [count+castx+castw+P1], [exscan x2 + W2a/W2b/bout]
//  - GEMM: dual A/B staged per k-iter (16 iters x 32 MFMA, barriers halved)
//  - agg: 8-edge unroll for MLP
//  - 7 total dispatches (memset + 6 kernels)

static constexpr int N0 = 100000;
static constexpr int N1 = 20000;
static constexpr int N2 = 4000;
static constexpr int HH = 512;
static constexpr int C  = 10;
static constexpr int M1PAD = 20096;  // 157 * 128

using frag  = __attribute__((ext_vector_type(8))) short;
using f32x4 = __attribute__((ext_vector_type(4))) float;

__device__ inline float bf2f(unsigned short u) {
    unsigned t = ((unsigned)u) << 16; float f; __builtin_memcpy(&f, &t, 4); return f;
}
__device__ inline unsigned short f2bf(float f) {
    unsigned u; __builtin_memcpy(&u, &f, 4);
    u += 0x7FFFu + ((u >> 16) & 1u);  // RNE
    return (unsigned short)(u >> 16);
}
__device__ inline void gld16(const void* g, void* l) {
    __builtin_amdgcn_global_load_lds((const __attribute__((address_space(1))) void*)g,
                                     (__attribute__((address_space(3))) void*)l,
                                     16, 0, 0);
}

// ---------------- prep1: edge-count atomics + x cast + weight cast + P1 -----
__global__ __launch_bounds__(256)
void prep1_k(const int* __restrict__ dst1, const int* __restrict__ dst2,
             int* __restrict__ cnt1, int* __restrict__ cnt2, int E1, int E2,
             const float* __restrict__ x, unsigned short* __restrict__ xb,
             const float* __restrict__ Wrel1, const float* __restrict__ Wroot1,
             unsigned short* __restrict__ Wt,
             const float* __restrict__ Wlin, const float* __restrict__ Whead,
             float* __restrict__ P1,
             int nbCount, int nbCast) {
    __shared__ float tsh[32][33];
    int b = blockIdx.x;
    if (b < nbCount) {                       // ---- edge counting (atomics) ----
        int g = b * 256 + threadIdx.x;
        if (g < E1) atomicAdd(&cnt1[dst1[g]], 1);
        else if (g < E1 + E2) atomicAdd(&cnt2[dst2[g - E1]], 1);
        return;
    }
    b -= nbCount;
    if (b < nbCast) {                        // ---- x -> bf16 (8 elem/thr) ----
        int g = b * 256 + threadIdx.x;
        const float4* p = (const float4*)x + (size_t)g * 2;
        float4 a = p[0], bb = p[1];
        unsigned short t[8] = {f2bf(a.x), f2bf(a.y), f2bf(a.z), f2bf(a.w),
                               f2bf(bb.x), f2bf(bb.y), f2bf(bb.z), f2bf(bb.w)};
        *(uint4*)(xb + (size_t)g * 8) = *(const uint4*)t;
        return;
    }
    b -= nbCast;
    if (b < 512) {                           // ---- weight transpose+cast ----
        int z = b >> 8, rem = b & 255;
        int bx = (rem & 15) * 32, by = (rem >> 4) * 32;
        const float* W = z ? Wroot1 : Wrel1;
        unsigned short* O = Wt + (size_t)z * HH * HH;
        int tx = threadIdx.x & 31, ty = threadIdx.x >> 5;
#pragma unroll
        for (int i = 0; i < 4; ++i)
            tsh[ty + i * 8][tx] = W[(size_t)(by + ty + i * 8) * HH + bx + tx];
        __syncthreads();
#pragma unroll
        for (int i = 0; i < 4; ++i)
            O[(size_t)(bx + ty + i * 8) * HH + by + tx] = f2bf(tsh[tx][ty + i * 8]);
        return;
    }
    b -= 512;
    {                                        // ---- P1 = Wlin @ Whead ----
        int g = b * 256 + threadIdx.x;
        if (g < HH * C) {
            int k = g / C, c = g % C;
            float acc = 0.f;
            const float* row = Wlin + (size_t)k * HH;
#pragma unroll 4
            for (int j = 0; j < HH; ++j) acc += row[j] * Whead[j * C + c];
            P1[g] = acc;
        }
    }
}

// ---------------- prep2: two exscans + W2aT/W2bT + bout ----------------
__global__ __launch_bounds__(1024)
void prep2_k(const int* __restrict__ cnt1, int* __restrict__ rs1,
             const int* __restrict__ cnt2, int* __restrict__ rs2,
             const float* __restrict__ Wrel2, const float* __restrict__ Wroot2,
             const float* __restrict__ P1,
             const float* __restrict__ brel2, const float* __restrict__ blin,
             const float* __restrict__ Whead, const float* __restrict__ bhead,
             float* __restrict__ W2aT, float* __restrict__ W2bT,
             float* __restrict__ bout) {
    __shared__ int part[1024];
    int blk = blockIdx.x;
    int t = threadIdx.x;
    if (blk < 2) {                           // ---- exclusive scans ----
        const int* cnt = blk ? cnt2 : cnt1;
        int* rs = blk ? rs2 : rs1;
        int n = blk ? N2 : N1;
        int chunk = (n + 1023) >> 10;
        int bb = t * chunk;
        int e = min(bb + chunk, n);
        int s = 0;
        for (int i = bb; i < e; ++i) s += cnt[i];
        part[t] = s;
        __syncthreads();
        for (int off = 1; off < 1024; off <<= 1) {
            int add = (t >= off) ? part[t - off] : 0;
            __syncthreads();
            part[t] += add;
            __syncthreads();
        }
        int base = (t == 0) ? 0 : part[t - 1];
        for (int i = bb; i < e; ++i) { rs[i] = base; base += cnt[i]; }
        if (t == 1023) rs[n] = part[1023];
        return;
    }
    if (blk < 12) {                          // ---- W2aT / W2bT ----
        int z = (blk - 2) >= 5;
        int g = (blk - 2 - z * 5) * 1024 + t;
        if (g < HH * C) {
            const float* W = z ? Wroot2 : Wrel2;
            float* O = z ? W2bT : W2aT;
            int k = g / C, c = g % C;
            float acc = 0.f;
            const float* row = W + (size_t)k * HH;
#pragma unroll 4
            for (int j = 0; j < HH; ++j) acc += row[j] * P1[j * C + c];
            O[c * HH + k] = acc;             // transposed [10][512]
        }
        return;
    }
    if (t < C) {                             // ---- bout ----
        float acc = bhead[t];
        for (int j = 0; j < HH; ++j)
            acc += brel2[j] * P1[j * C + t] + blin[j] * Whead[j * C + t];
        bout[t] = acc;
    }
}

// ---------------- CSR fill (both layers) ----------------
__global__ void fill_both_k(const int* __restrict__ src1, const int* __restrict__ dst1,
                            const int* __restrict__ src2, const int* __restrict__ dst2,
                            const int* __restrict__ rs1, const int* __restrict__ rs2,
                            int* __restrict__ cur1, int* __restrict__ cur2,
                            int* __restrict__ eidx1, int* __restrict__ eidx2,
                            int E1, int E2) {
    int g = blockIdx.x * 256 + threadIdx.x;
    if (g < E1) {
        int d = dst1[g];
        int pos = atomicAdd(&cur1[d], 1);
        eidx1[rs1[d] + pos] = src1[g];
    } else if (g < E1 + E2) {
        int gg = g - E1;
        int d = dst2[gg];
        int pos = atomicAdd(&cur2[d], 1);
        eidx2[rs2[d] + pos] = src2[gg];
    }
}

// ---------------- aggregation: one wave per node, 8-edge unroll ----------------
__global__ __launch_bounds__(256)
void agg_bf16_k(const unsigned short* __restrict__ x, const int* __restrict__ rs,
                const int* __restrict__ eidx, unsigned short* __restrict__ out, int n) {
    int node = blockIdx.x * 4 + (threadIdx.x >> 6);
    if (node >= n) return;
    int l = threadIdx.x & 63;
    int s = rs[node], e = rs[node + 1];
    float acc[8] = {};
    int i = s;
    for (; i + 8 <= e; i += 8) {
        uint4 v[8];
#pragma unroll
        for (int u = 0; u < 8; ++u)
            v[u] = *(const uint4*)(x + (size_t)eidx[i + u] * HH + l * 8);
#pragma unroll
        for (int u = 0; u < 8; ++u) {
            const unsigned short* pv = (const unsigned short*)&v[u];
#pragma unroll
            for (int j = 0; j < 8; ++j) acc[j] += bf2f(pv[j]);
        }
    }
    for (; i < e; ++i) {
        uint4 a = *(const uint4*)(x + (size_t)eidx[i] * HH + l * 8);
        const unsigned short* pa = (const unsigned short*)&a;
#pragma unroll
        for (int j = 0; j < 8; ++j) acc[j] += bf2f(pa[j]);
    }
    unsigned short o[8];
#pragma unroll
    for (int j = 0; j < 8; ++j) o[j] = f2bf(acc[j]);
    *(uint4*)(out + (size_t)node * HH + l * 8) = *(const uint4*)o;
}

// ---------------- bf16 MFMA GEMM (layer 1, dual fused in k-loop) ----------------
// h = relu(agg1@Wrel1^T' + x@Wroot1^T' + b); Bt inputs are [N][K] bf16.
__global__ __launch_bounds__(256)
void gemm_mfma_k(const short* __restrict__ A1, const short* __restrict__ B1t,
                 const short* __restrict__ A2, const short* __restrict__ B2t,
                 const float* __restrict__ bias, unsigned short* __restrict__ Cout,
                 int M) {
    __shared__ __align__(16) short Ls[4 * 128 * 32];   // A1 | A2 | B1 | B2 (32 KB)
    short* As1 = Ls;
    short* As2 = Ls + 4096;
    short* Bs1 = Ls + 8192;
    short* Bs2 = Ls + 12288;
    const int bn = blockIdx.x * 128;
    const int bm = blockIdx.y * 128;
    const int tid = threadIdx.x;
    const int lane = tid & 63;
    const int wave = tid >> 6;
    const int l15 = lane & 15;
    const int quad = lane >> 4;
    const int wm = (wave >> 1) * 64;
    const int wn = (wave & 1) * 64;
    const int r0 = tid >> 2;          // 0..63
    const int sg = (tid & 3) * 8;     // bf16 offset in 32-k row

    f32x4 acc[4][4] = {};

    for (int k0 = 0; k0 < 512; k0 += 32) {
        gld16(A1 + (size_t)(bm + r0) * 512 + k0 + sg,        As1 + tid * 8);
        gld16(A1 + (size_t)(bm + r0 + 64) * 512 + k0 + sg,   As1 + (tid + 256) * 8);
        gld16(A2 + (size_t)(bm + r0) * 512 + k0 + sg,        As2 + tid * 8);
        gld16(A2 + (size_t)(bm + r0 + 64) * 512 + k0 + sg,   As2 + (tid + 256) * 8);
        gld16(B1t + (size_t)(bn + r0) * 512 + k0 + sg,       Bs1 + tid * 8);
        gld16(B1t + (size_t)(bn + r0 + 64) * 512 + k0 + sg,  Bs1 + (tid + 256) * 8);
        gld16(B2t + (size_t)(bn + r0) * 512 + k0 + sg,       Bs2 + tid * 8);
        gld16(B2t + (size_t)(bn + r0 + 64) * 512 + k0 + sg,  Bs2 + (tid + 256) * 8);
        __syncthreads();
        {
            frag a[4], b[4];
#pragma unroll
            for (int mi = 0; mi < 4; ++mi)
                a[mi] = *(const frag*)(As1 + (wm + mi * 16 + l15) * 32 + quad * 8);
#pragma unroll
            for (int ni = 0; ni < 4; ++ni)
                b[ni] = *(const frag*)(Bs1 + (wn + ni * 16 + l15) * 32 + quad * 8);
#pragma unroll
            for (int mi = 0; mi < 4; ++mi)
#pragma unroll
                for (int ni = 0; ni < 4; ++ni)
                    acc[mi][ni] = __builtin_amdgcn_mfma_f32_16x16x32_bf16(
                        a[mi], b[ni], acc[mi][ni], 0, 0, 0);
#pragma unroll
            for (int mi = 0; mi < 4; ++mi)
                a[mi] = *(const frag*)(As2 + (wm + mi * 16 + l15) * 32 + quad * 8);
#pragma unroll
            for (int ni = 0; ni < 4; ++ni)
                b[ni] = *(const frag*)(Bs2 + (wn + ni * 16 + l15) * 32 + quad * 8);
#pragma unroll
            for (int mi = 0; mi < 4; ++mi)
#pragma unroll
                for (int ni = 0; ni < 4; ++ni)
                    acc[mi][ni] = __builtin_amdgcn_mfma_f32_16x16x32_bf16(
                        a[mi], b[ni], acc[mi][ni], 0, 0, 0);
        }
        __syncthreads();
    }

#pragma unroll
    for (int ni = 0; ni < 4; ++ni) {
        const int gn = bn + wn + ni * 16 + l15;
        const float bv = bias[gn];
#pragma unroll
        for (int mi = 0; mi < 4; ++mi) {
            const int gm0 = bm + wm + mi * 16 + quad * 4;
#pragma unroll
            for (int r = 0; r < 4; ++r) {
                const int gm = gm0 + r;
                if (gm < M) {
                    float v = fmaxf(acc[mi][ni][r] + bv, 0.f);
                    Cout[(size_t)gm * 512 + gn] = f2bf(v);
                }
            }
        }
    }
}

// ---------------- fused tail: gather + [512,10] matvec -> out ----------------
__global__ __launch_bounds__(256)
void tail_k(const unsigned short* __restrict__ h, const int* __restrict__ rs,
            const int* __restrict__ eidx,
            const float* __restrict__ W2aT, const float* __restrict__ W2bT,
            const float* __restrict__ bout, float* __restrict__ out) {
    int node = blockIdx.x * 4 + (threadIdx.x >> 6);
    if (node >= N2) return;
    int l = threadIdx.x & 63;
    int s = rs[node], e = rs[node + 1];
    float acc[8] = {};
    int i = s;
    for (; i + 4 <= e; i += 4) {
        uint4 v[4];
#pragma unroll
        for (int u = 0; u < 4; ++u)
            v[u] = *(const uint4*)(h + (size_t)eidx[i + u] * HH + l * 8);
#pragma unroll
        for (int u = 0; u < 4; ++u) {
            const unsigned short* pv = (const unsigned short*)&v[u];
#pragma unroll
            for (int j = 0; j < 8; ++j) acc[j] += bf2f(pv[j]);
        }
    }
    for (; i < e; ++i) {
        uint4 a = *(const uint4*)(h + (size_t)eidx[i] * HH + l * 8);
        const unsigned short* pa = (const unsigned short*)&a;
#pragma unroll
        for (int j = 0; j < 8; ++j) acc[j] += bf2f(pa[j]);
    }
    float r[8];
    {
        uint4 a = *(const uint4*)(h + (size_t)node * HH + l * 8);
        const unsigned short* pa = (const unsigned short*)&a;
#pragma unroll
        for (int j = 0; j < 8; ++j) r[j] = bf2f(pa[j]);
    }
    float p[C];
#pragma unroll
    for (int c = 0; c < C; ++c) {
        const float* wa = W2aT + c * HH + l * 8;
        const float* wb = W2bT + c * HH + l * 8;
        float4 wa0 = *(const float4*)wa, wa1 = *(const float4*)(wa + 4);
        float4 wb0 = *(const float4*)wb, wb1 = *(const float4*)(wb + 4);
        float v = acc[0] * wa0.x + acc[1] * wa0.y + acc[2] * wa0.z + acc[3] * wa0.w
                + acc[4] * wa1.x + acc[5] * wa1.y + acc[6] * wa1.z + acc[7] * wa1.w
                + r[0] * wb0.x + r[1] * wb0.y + r[2] * wb0.z + r[3] * wb0.w
                + r[4] * wb1.x + r[5] * wb1.y + r[6] * wb1.z + r[7] * wb1.w;
#pragma unroll
        for (int off = 32; off; off >>= 1) v += __shfl_xor(v, off);
        p[c] = v;
    }
    if (l == 0) {
#pragma unroll
        for (int c = 0; c < C; ++c) out[(size_t)node * C + c] = p[c] + bout[c];
    }
}

extern "C" void kernel_launch(void* const* d_in, const int* in_sizes, int n_in,
                              void* d_out, int out_size, void* d_ws, size_t ws_size,
                              hipStream_t stream) {
    const float* x      = (const float*)d_in[0];
    const int*   src1   = (const int*)d_in[1];
    const int*   dst1   = (const int*)d_in[2];
    const int*   src2   = (const int*)d_in[3];
    const int*   dst2   = (const int*)d_in[4];
    const float* Wrel1  = (const float*)d_in[5];
    const float* brel1  = (const float*)d_in[6];
    const float* Wroot1 = (const float*)d_in[7];
    const float* Wrel2  = (const float*)d_in[8];
    const float* brel2  = (const float*)d_in[9];
    const float* Wroot2 = (const float*)d_in[10];
    const float* Wlin   = (const float*)d_in[11];
    const float* blin   = (const float*)d_in[12];
    const float* Whead  = (const float*)d_in[13];
    const float* bhead  = (const float*)d_in[14];
    float* out = (float*)d_out;

    const int E1 = in_sizes[1];
    const int E2 = in_sizes[3];

    // ---- workspace layout (~147 MB; ws is ~800 MB per fill evidence) ----
    char* w = (char*)d_ws;
    auto alloc = [&](size_t bytes) { char* p = w; w += (bytes + 255) & ~(size_t)255; return p; };
    unsigned short* xb    = (unsigned short*)alloc((size_t)N0 * HH * 2);
    unsigned short* agg1b = (unsigned short*)alloc((size_t)M1PAD * HH * 2);
    unsigned short* hb    = (unsigned short*)alloc((size_t)M1PAD * HH * 2);
    unsigned short* Wt    = (unsigned short*)alloc((size_t)2 * HH * HH * 2);
    float* P1    = (float*)alloc((size_t)HH * C * 4);
    float* W2aT  = (float*)alloc((size_t)HH * C * 4);
    float* W2bT  = (float*)alloc((size_t)HH * C * 4);
    float* boutp = (float*)alloc(256);
    int* ip = (int*)alloc((size_t)(2 * N1 + 2 * N2 + (N1 + 1) + (N2 + 1) + E1 + E2) * 4);
    int* cnt1  = ip;
    int* cur1  = ip + N1;
    int* cnt2  = ip + 2 * N1;
    int* cur2  = ip + 2 * N1 + N2;
    int* rs1   = ip + 2 * N1 + 2 * N2;
    int* rs2   = rs1 + N1 + 1;
    int* eidx1 = rs2 + N2 + 1;
    int* eidx2 = eidx1 + E1;

    const short* Wrel1t  = (const short*)(Wt);
    const short* Wroot1t = (const short*)(Wt + (size_t)HH * HH);

    hipMemsetAsync(ip, 0, (size_t)(2 * N1 + 2 * N2) * sizeof(int), stream);

    // ---- prep1: count + castx + castw + P1 ----
    const int nbCount = (E1 + E2 + 255) / 256;
    const int nbCast  = N0 * HH / 8 / 256;   // 25000
    const int nbP1    = (HH * C + 255) / 256;
    prep1_k<<<nbCount + nbCast + 512 + nbP1, 256, 0, stream>>>(
        dst1, dst2, cnt1, cnt2, E1, E2, x, xb, Wrel1, Wroot1, Wt,
        Wlin, Whead, P1, nbCount, nbCast);

    // ---- prep2: exscans + W2aT/W2bT + bout ----
    prep2_k<<<13, 1024, 0, stream>>>(cnt1, rs1, cnt2, rs2, Wrel2, Wroot2, P1,
                                     brel2, blin, Whead, bhead, W2aT, W2bT, boutp);

    // ---- CSR fill ----
    fill_both_k<<<nbCount, 256, 0, stream>>>(src1, dst1, src2, dst2, rs1, rs2,
                                             cur1, cur2, eidx1, eidx2, E1, E2);

    // ---- layer 1 ----
    agg_bf16_k<<<(N1 + 3) / 4, 256, 0, stream>>>(xb, rs1, eidx1, agg1b, N1);
    {
        dim3 grid(HH / 128, M1PAD / 128);
        gemm_mfma_k<<<grid, 256, 0, stream>>>(
            (const short*)agg1b, Wrel1t, (const short*)xb, Wroot1t, brel1, hb, N1);
    }

    // ---- fused layer 2 + head ----
    tail_k<<<(N2 + 3) / 4, 256, 0, stream>>>(hb, rs2, eidx2, W2aT, W2bT, boutp, out);
}